// Round 11
// baseline (86.599 us; speedup 1.0000x reference)
//
#include <hip/hip_runtime.h>

#define BATCH 1024
#define INSZ 4096
#define NH 8
#define TPB 256
#define LDT 40    // [*][32] tiles stride (elems)
#define LDV 136   // vT [32][128] stride (elems)

typedef __attribute__((ext_vector_type(8))) __bf16 bf16x8;
typedef __attribute__((ext_vector_type(4))) __bf16 bf16x4;
typedef __attribute__((ext_vector_type(4))) float f32x4;

// LDS map (bf16 elem offsets):
//   XN [0,5120)        xn [128][LDT] (read wave-locally by proj, all heads)
//   QW [5120,10240)    per-wave q [32][LDT] at QW+wid*1280 (wave-local)
//   KS [10240,20480)   K [128][LDT], head-parity dbuf (cross-wave)
//   VS [20480,29184)   vT [32][LDV], head-parity dbuf (cross-wave)
//   DN byte 58368      denom partials f32 [2 parity][4 wave][128 j] (4 KB)
//   RD byte 62464      LN scratch 16 f32
// Total 62528 B -> 2 blocks/CU.
#define XN 0
#define QW 5120
#define KS 10240
#define VS 20480
#define DNB 58368
#define RDB 62464

// 1/sqrt(32)*log2(e): folded into wq (cvt_w) + bq seed; scores emerge pre-scaled
// for exp2. Softmax over the QUERY axis uses m=0 (shift-invariant, |s| O(5)).
#define CQ 0.25505644061151687f

__global__ void cvt_w(const float* __restrict__ wq, const float* __restrict__ wk,
                      const float* __restrict__ wv, const float* __restrict__ wo,
                      __bf16* __restrict__ ws) {
  int i = blockIdx.x * blockDim.x + threadIdx.x;  // 0..32767
  const float* src = (i < 8192) ? wq : (i < 16384) ? wk : (i < 24576) ? wv : wo;
  float v = src[i & 8191];
  if (i < 8192) v *= CQ;
  ws[i] = (__bf16)v;
}

// 16-lane butterfly sum on the VALU pipe (DPP), no LDS traffic.
__device__ __forceinline__ float row_reduce_add16(float v) {
  int t;
  t = __builtin_amdgcn_update_dpp(0, __float_as_int(v), 0xB1, 0xF, 0xF, true);
  v += __int_as_float(t);
  t = __builtin_amdgcn_update_dpp(0, __float_as_int(v), 0x4E, 0xF, 0xF, true);
  v += __int_as_float(t);
  t = __builtin_amdgcn_update_dpp(0, __float_as_int(v), 0x141, 0xF, 0xF, true);
  v += __int_as_float(t);
  t = __builtin_amdgcn_update_dpp(0, __float_as_int(v), 0x140, 0xF, 0xF, true);
  v += __int_as_float(t);
  return v;
}

__global__ __launch_bounds__(TPB, 2) void mha_fused(
    const float* __restrict__ x, const float* __restrict__ gamma,
    const float* __restrict__ beta, const float* __restrict__ bq,
    const float* __restrict__ bk, const float* __restrict__ bv,
    const float* __restrict__ bo, const __bf16* __restrict__ wbf,
    float* __restrict__ out) {
  __shared__ __align__(16) __bf16 R[31264];  // 62528 B

  const int b = blockIdx.x;
  const int tid = threadIdx.x;
  const int lane = tid & 63;
  const int wid = tid >> 6;   // wave owns queries [32w,32w+32) and stages keys [32w,32w+32)
  const int l15 = lane & 15;
  const int lh = lane >> 4;   // 0..3

  const __bf16* wqb = wbf;
  const __bf16* wkb = wbf + 8192;
  const __bf16* wvb = wbf + 16384;
  const __bf16* wob = wbf + 24576;  // [32][256] row-major

  const float* xb = x + b * INSZ;
  const f32x4 fz = {0.f, 0.f, 0.f, 0.f};

  float* dn = (float*)((char*)R + DNB);
  float* red2 = (float*)((char*)R + RDB);

  // ---------------- LayerNorm (16 elems/thread) ----------------
  float xv[16];
  float s = 0.f, sq = 0.f;
#pragma unroll
  for (int i = 0; i < 4; ++i) {
    float4 a = ((const float4*)(xb + tid * 16))[i];
    xv[4 * i] = a.x; xv[4 * i + 1] = a.y; xv[4 * i + 2] = a.z; xv[4 * i + 3] = a.w;
  }
#pragma unroll
  for (int i = 0; i < 16; ++i) { s += xv[i]; sq += xv[i] * xv[i]; }
#pragma unroll
  for (int o = 32; o > 0; o >>= 1) { s += __shfl_down(s, o); sq += __shfl_down(sq, o); }
  if (lane == 0) { red2[wid] = s; red2[4 + wid] = sq; }
  __syncthreads();
  s = red2[0] + red2[1] + red2[2] + red2[3];
  sq = red2[4] + red2[5] + red2[6] + red2[7];
  const float mu = s * (1.f / INSZ);
  const float var = fmaxf(sq * (1.f / INSZ) - mu * mu, 0.f);
  const float rs = rsqrtf(var + 1e-5f);
  {
    int base = tid * 16;
#pragma unroll
    for (int i = 0; i < 4; ++i) {
      float4 g4 = ((const float4*)(gamma + base))[i];
      float4 b4 = ((const float4*)(beta + base))[i];
      float gg[4] = {g4.x, g4.y, g4.z, g4.w};
      float bb[4] = {b4.x, b4.y, b4.z, b4.w};
#pragma unroll
      for (int k = 0; k < 4; ++k) {
        int idx = base + 4 * i + k;
        float xn = (xv[4 * i + k] - mu) * rs * gg[k] + bb[k];
        R[XN + (idx >> 5) * LDT + (idx & 31)] = (__bf16)xn;  // wave-local rows
      }
    }
  }
  // No barrier: proj reads only this wave's own xn rows.

  const int qb = wid * 32;
  __bf16* qw = &R[QW + wid * 1280];

  // xn fragments (wave's own 32 rows), head-invariant.
  bf16x8 tA0 = *(const bf16x8*)&R[XN + (qb + l15) * LDT + lh * 8];
  bf16x8 tA1 = *(const bf16x8*)&R[XN + (qb + 16 + l15) * LDT + lh * 8];

  // oacc[nt][it]: D[e'][i], e'=nt*16+lh*4+r, i=qb+it*16+l15; seeded with bo(e').
  f32x4 oacc[2][2];
  {
    f32x4 b0 = *(const f32x4*)&bo[lh * 4];
    f32x4 b1 = *(const f32x4*)&bo[16 + lh * 4];
    oacc[0][0] = b0; oacc[0][1] = b0;
    oacc[1][0] = b1; oacc[1][1] = b1;
  }

  // Project head hh: q (wave-local), K rows [qb,qb+32), vT cols [qb,qb+32).
  auto do_proj = [&](int hh, int p) {
    const int f0 = hh * 32;
    __bf16* Kp = &R[KS + p * 5120];
    __bf16* Vp = &R[VS + p * 4352];
#pragma unroll
    for (int ft = 0; ft < 2; ++ft) {
      int fb = f0 + ft * 16;
      bf16x8 wqf = *(const bf16x8*)&wqb[(fb + l15) * 32 + lh * 8];
      bf16x8 wkf = *(const bf16x8*)&wkb[(fb + l15) * 32 + lh * 8];
      f32x4 bq4 = *(const f32x4*)&bq[fb + lh * 4];
      f32x4 bk4 = *(const f32x4*)&bk[fb + lh * 4];
#pragma unroll
      for (int r = 0; r < 4; ++r) bq4[r] *= CQ;
#pragma unroll
      for (int st = 0; st < 2; ++st) {
        bf16x8 tB = (st == 0) ? tA0 : tA1;
        // D[f][s]: f = fb+lh*4+r, s = qb+st*16+l15; C seed = bias(f)
        f32x4 dq = __builtin_amdgcn_mfma_f32_16x16x32_bf16(wqf, tB, bq4, 0, 0, 0);
        f32x4 dk = __builtin_amdgcn_mfma_f32_16x16x32_bf16(wkf, tB, bk4, 0, 0, 0);
        bf16x4 pq, pk;
#pragma unroll
        for (int r = 0; r < 4; ++r) { pq[r] = (__bf16)dq[r]; pk[r] = (__bf16)dk[r]; }
        *(bf16x4*)&qw[(st * 16 + l15) * LDT + ft * 16 + lh * 4] = pq;
        *(bf16x4*)&Kp[(qb + st * 16 + l15) * LDT + ft * 16 + lh * 4] = pk;
      }
    }
#pragma unroll
    for (int nt = 0; nt < 2; ++nt) {
      int fb = f0 + nt * 16;
      bf16x8 wvf = *(const bf16x8*)&wvb[(fb + l15) * 32 + lh * 8];
      float bvs = bv[fb + l15];
      f32x4 bv4 = {bvs, bvs, bvs, bvs};
#pragma unroll
      for (int mt = 0; mt < 2; ++mt) {
        bf16x8 tA = (mt == 0) ? tA0 : tA1;
        // D[s][f]: s = qb+mt*16+lh*4+r, f = fb+l15
        f32x4 dv = __builtin_amdgcn_mfma_f32_16x16x32_bf16(tA, wvf, bv4, 0, 0, 0);
        bf16x4 pv;
#pragma unroll
        for (int r = 0; r < 4; ++r) pv[r] = (__bf16)dv[r];
        *(bf16x4*)&Vp[(nt * 16 + l15) * LDV + qb + mt * 16 + lh * 4] = pv;
      }
    }
  };

  do_proj(0, 0);

  for (int h = 0; h < NH; ++h) {
    const int p = h & 1;
    const __bf16* Kp = &R[KS + p * 5120];
    const __bf16* Vp = &R[VS + p * 4352];
    float* dnp = dn + p * 512;
    __syncthreads();  // A: K[p], vT[p] staged by all waves

    // ---------- scoresT = K·q^T over ALL keys, wave's 32 queries ----------
    // st2[it][jt]: D[j][i], j = jt*16+lh*4+r, i = qb+it*16+l15
    bf16x8 qf0 = *(const bf16x8*)&qw[(l15) * LDT + lh * 8];
    bf16x8 qf1 = *(const bf16x8*)&qw[(16 + l15) * LDT + lh * 8];
    f32x4 st2[2][8];
    __builtin_amdgcn_s_setprio(1);
#pragma unroll
    for (int jt = 0; jt < 8; ++jt) {
      bf16x8 kf = *(const bf16x8*)&Kp[(jt * 16 + l15) * LDT + lh * 8];
      st2[0][jt] = __builtin_amdgcn_mfma_f32_16x16x32_bf16(kf, qf0, fz, 0, 0, 0);
      st2[1][jt] = __builtin_amdgcn_mfma_f32_16x16x32_bf16(kf, qf1, fz, 0, 0, 0);
    }
    __builtin_amdgcn_s_setprio(0);

    // ---------- project NEXT head into opposite buffers (fills latency) ----------
    if (h < NH - 1) do_proj(h + 1, p ^ 1);

    // ---------- softmax partials (query axis): exp2 + per-wave column sums ----------
#pragma unroll
    for (int jt = 0; jt < 8; ++jt) {
      f32x4 part;
#pragma unroll
      for (int r = 0; r < 4; ++r) {
        float e0 = __builtin_amdgcn_exp2f(st2[0][jt][r]);
        float e1 = __builtin_amdgcn_exp2f(st2[1][jt][r]);
        st2[0][jt][r] = e0;
        st2[1][jt][r] = e1;
        part[r] = row_reduce_add16(e0 + e1);
      }
      if (l15 == 0) *(f32x4*)&dnp[wid * 128 + jt * 16 + lh * 4] = part;
    }
    __syncthreads();  // B: denom partials ready

    // ---------- PV entirely from registers (permuted-k K=32 MFMA) ----------
    // virtual k = lh*8+e  <->  j = (2jp + (e>=4))*16 + lh*4 + (e&3); A,B share it.
    f32x4 p2[2][2];
#pragma unroll
    for (int i = 0; i < 2; ++i)
#pragma unroll
      for (int j = 0; j < 2; ++j) p2[i][j] = fz;
#pragma unroll
    for (int jp = 0; jp < 4; ++jp) {
      int jA = 2 * jp, jB = 2 * jp + 1;
      // denom: sum 4 wave-partials, broadcast reads over l15
      f32x4 sA = *(const f32x4*)&dnp[0 * 128 + jA * 16 + lh * 4];
      f32x4 sB = *(const f32x4*)&dnp[0 * 128 + jB * 16 + lh * 4];
#pragma unroll
      for (int w = 1; w < 4; ++w) {
        sA += *(const f32x4*)&dnp[w * 128 + jA * 16 + lh * 4];
        sB += *(const f32x4*)&dnp[w * 128 + jB * 16 + lh * 4];
      }
      f32x4 ivA, ivB;
#pragma unroll
      for (int r = 0; r < 4; ++r) {
        ivA[r] = __builtin_amdgcn_rcpf(sA[r]);
        ivB[r] = __builtin_amdgcn_rcpf(sB[r]);
      }
      // B-frags: P^T values straight from st2 registers
      bf16x8 pb0, pb1;
#pragma unroll
      for (int e = 0; e < 4; ++e) {
        pb0[e] = (__bf16)(st2[0][jA][e] * ivA[e]);
        pb0[4 + e] = (__bf16)(st2[0][jB][e] * ivB[e]);
        pb1[e] = (__bf16)(st2[1][jA][e] * ivA[e]);
        pb1[4 + e] = (__bf16)(st2[1][jB][e] * ivB[e]);
      }
      // A-frags: vT with the same virtual-k permutation (two b64 reads each)
      bf16x4 a0A = *(const bf16x4*)&Vp[(l15) * LDV + jA * 16 + lh * 4];
      bf16x4 a0B = *(const bf16x4*)&Vp[(l15) * LDV + jB * 16 + lh * 4];
      bf16x4 a1A = *(const bf16x4*)&Vp[(16 + l15) * LDV + jA * 16 + lh * 4];
      bf16x4 a1B = *(const bf16x4*)&Vp[(16 + l15) * LDV + jB * 16 + lh * 4];
      bf16x8 va0, va1;
#pragma unroll
      for (int e = 0; e < 4; ++e) {
        va0[e] = a0A[e]; va0[4 + e] = a0B[e];
        va1[e] = a1A[e]; va1[4 + e] = a1B[e];
      }
      __builtin_amdgcn_s_setprio(1);
      p2[0][0] = __builtin_amdgcn_mfma_f32_16x16x32_bf16(va0, pb0, p2[0][0], 0, 0, 0);
      p2[0][1] = __builtin_amdgcn_mfma_f32_16x16x32_bf16(va0, pb1, p2[0][1], 0, 0, 0);
      p2[1][0] = __builtin_amdgcn_mfma_f32_16x16x32_bf16(va1, pb0, p2[1][0], 0, 0, 0);
      p2[1][1] = __builtin_amdgcn_mfma_f32_16x16x32_bf16(va1, pb1, p2[1][1], 0, 0, 0);
      __builtin_amdgcn_s_setprio(0);
    }

    // ---------- outproj from registers (same permuted-k trick over e) ----------
    // virtual k = lh*8+e <-> embed = (e>=4 ? 16:0) + lh*4 + (e&3)
    {
      bf16x4 w0A = *(const bf16x4*)&wob[(l15) * 256 + h * 32 + lh * 4];
      bf16x4 w0B = *(const bf16x4*)&wob[(l15) * 256 + h * 32 + 16 + lh * 4];
      bf16x4 w1A = *(const bf16x4*)&wob[(16 + l15) * 256 + h * 32 + lh * 4];
      bf16x4 w1B = *(const bf16x4*)&wob[(16 + l15) * 256 + h * 32 + 16 + lh * 4];
      bf16x8 woA0, woA1, pbo0, pbo1;
#pragma unroll
      for (int e = 0; e < 4; ++e) {
        woA0[e] = w0A[e]; woA0[4 + e] = w0B[e];
        woA1[e] = w1A[e]; woA1[4 + e] = w1B[e];
        pbo0[e] = (__bf16)p2[0][0][e]; pbo0[4 + e] = (__bf16)p2[1][0][e];
        pbo1[e] = (__bf16)p2[0][1][e]; pbo1[4 + e] = (__bf16)p2[1][1][e];
      }
      oacc[0][0] = __builtin_amdgcn_mfma_f32_16x16x32_bf16(woA0, pbo0, oacc[0][0], 0, 0, 0);
      oacc[0][1] = __builtin_amdgcn_mfma_f32_16x16x32_bf16(woA0, pbo1, oacc[0][1], 0, 0, 0);
      oacc[1][0] = __builtin_amdgcn_mfma_f32_16x16x32_bf16(woA1, pbo0, oacc[1][0], 0, 0, 0);
      oacc[1][1] = __builtin_amdgcn_mfma_f32_16x16x32_bf16(woA1, pbo1, oacc[1][1], 0, 0, 0);
    }
    // No trailing barrier: next iteration's barrier A orders parity buffers;
    // dn[p] is re-written only after the following A (two barriers away).
  }

  // ---------------- epilogue: + x (bo already seeded) ----------------
#pragma unroll
  for (int nt = 0; nt < 2; ++nt)
#pragma unroll
    for (int it = 0; it < 2; ++it) {
      int idx = (qb + it * 16 + l15) * 32 + nt * 16 + lh * 4;
      f32x4 xr = *(const f32x4*)&xb[idx];
      *(f32x4*)&out[b * INSZ + idx] = oacc[nt][it] + xr;
    }
}

extern "C" void kernel_launch(void* const* d_in, const int* in_sizes, int n_in,
                              void* d_out, int out_size, void* d_ws, size_t ws_size,
                              hipStream_t stream) {
  const float* x = (const float*)d_in[0];
  const float* gamma = (const float*)d_in[1];
  const float* beta = (const float*)d_in[2];
  const float* wq = (const float*)d_in[3];
  const float* bq = (const float*)d_in[4];
  const float* wk = (const float*)d_in[5];
  const float* bk = (const float*)d_in[6];
  const float* wv = (const float*)d_in[7];
  const float* bv = (const float*)d_in[8];
  const float* wo = (const float*)d_in[9];
  const float* bo = (const float*)d_in[10];
  float* out = (float*)d_out;
  __bf16* wsb = (__bf16*)d_ws;

  cvt_w<<<128, 256, 0, stream>>>(wq, wk, wv, wo, wsb);
  mha_fused<<<BATCH, TPB, 0, stream>>>(x, gamma, beta, bq, bk, bv, bo, wsb, out);
}

// Round 12
// 67.307 us; speedup vs baseline: 1.2866x; 1.2866x over previous
//
#include <hip/hip_runtime.h>

#define BATCH 1024
#define INSZ 4096
#define SQ 128
#define EM 32
#define NH 8
#define TPB 256

typedef __attribute__((ext_vector_type(8))) __bf16 bf16x8;
typedef __attribute__((ext_vector_type(4))) __bf16 bf16x4;
typedef __attribute__((ext_vector_type(4))) float f32x4;

// Unified LDS region, element offsets (bf16):
//   Q0 [0,5120)       q-stage parity0 [128][LDT=40] (xn overlay pre-loop)
//   Q1 [5120,10240)   q-stage parity1
//   KP [10240,15360)  K-stage [128][LDT] — wave-local rows, consumed to regs
//   V0 [15360,19456)  vT parity0 [32][128] swizzled
//   V1 [19456,23552)  vT parity1
//   PO [23552,39936)  P [128][128] swizzled (16384) — single buffer; A(h+1)
//                     separates PV(h) reads from P-store(h+1) writes
//   RD [39936,39952)  LN reduction scratch (32 B)
#define LDT 40
#define Q0 0
#define Q1 5120
#define KP 10240
#define V0 15360
#define V1 19456
#define PO 23552
#define RD 39936

// 1/sqrt(32) * log2(e): folded into wq (cvt_w) and bq seed; scores emerge
// pre-scaled for exp2. Softmax uses m=0 (shift-invariant; |scores| O(5)).
#define CQ 0.25505644061151687f

__global__ void cvt_w(const float* __restrict__ wq, const float* __restrict__ wk,
                      const float* __restrict__ wv, const float* __restrict__ wo,
                      __bf16* __restrict__ ws) {
  int i = blockIdx.x * blockDim.x + threadIdx.x;  // 0..32767
  const float* src = (i < 8192) ? wq : (i < 16384) ? wk : (i < 24576) ? wv : wo;
  float v = src[i & 8191];
  if (i < 8192) v *= CQ;
  ws[i] = (__bf16)v;
}

// 16-lane butterfly sum on the VALU pipe (DPP), no LDS traffic.
__device__ __forceinline__ float row_reduce_add16(float v) {
  int t;
  t = __builtin_amdgcn_update_dpp(0, __float_as_int(v), 0xB1, 0xF, 0xF, true);
  v += __int_as_float(t);
  t = __builtin_amdgcn_update_dpp(0, __float_as_int(v), 0x4E, 0xF, 0xF, true);
  v += __int_as_float(t);
  t = __builtin_amdgcn_update_dpp(0, __float_as_int(v), 0x141, 0xF, 0xF, true);
  v += __int_as_float(t);
  t = __builtin_amdgcn_update_dpp(0, __float_as_int(v), 0x140, 0xF, 0xF, true);
  v += __int_as_float(t);
  return v;
}

__global__ __launch_bounds__(TPB, 2) void mha_fused(
    const float* __restrict__ x, const float* __restrict__ gamma,
    const float* __restrict__ beta, const float* __restrict__ bq,
    const float* __restrict__ bk, const float* __restrict__ bv,
    const float* __restrict__ bo, const __bf16* __restrict__ wbf,
    float* __restrict__ out) {
  __shared__ __align__(16) __bf16 R[39952];  // 79904 B

  const int b = blockIdx.x;
  const int tid = threadIdx.x;
  const int lane = tid & 63;
  const int wid = tid >> 6;   // 4 waves; wave w owns s-rows [32w, 32w+32)
  const int l15 = lane & 15;
  const int lh = lane >> 4;   // 0..3
  const int sw = (l15 & 7) << 3;  // XOR swizzle (elems) for 256B-stride tiles

  const __bf16* wqb = wbf;
  const __bf16* wkb = wbf + 8192;
  const __bf16* wvb = wbf + 16384;
  const __bf16* wob = wbf + 24576;  // [32][256] row-major

  const float* xb = x + b * INSZ;
  const f32x4 fz = {0.f, 0.f, 0.f, 0.f};

  float* red2 = (float*)&R[RD];

  // ---------------- LayerNorm ----------------
  float xv[16];
  float s = 0.f, sq = 0.f;
#pragma unroll
  for (int i = 0; i < 4; ++i) {
    float4 a = ((const float4*)(xb + tid * 16))[i];
    xv[4 * i] = a.x; xv[4 * i + 1] = a.y; xv[4 * i + 2] = a.z; xv[4 * i + 3] = a.w;
  }
#pragma unroll
  for (int i = 0; i < 16; ++i) { s += xv[i]; sq += xv[i] * xv[i]; }
#pragma unroll
  for (int o = 32; o > 0; o >>= 1) { s += __shfl_down(s, o); sq += __shfl_down(sq, o); }
  if (lane == 0) { red2[wid] = s; red2[4 + wid] = sq; }
  __syncthreads();
  s = red2[0] + red2[1] + red2[2] + red2[3];
  sq = red2[4] + red2[5] + red2[6] + red2[7];
  const float mu = s * (1.f / INSZ);
  const float var = fmaxf(sq * (1.f / INSZ) - mu * mu, 0.f);
  const float rs = rsqrtf(var + 1e-5f);
  {
    int base = tid * 16;
#pragma unroll
    for (int i = 0; i < 4; ++i) {
      float4 g4 = ((const float4*)(gamma + base))[i];
      float4 b4 = ((const float4*)(beta + base))[i];
      float gg[4] = {g4.x, g4.y, g4.z, g4.w};
      float bb[4] = {b4.x, b4.y, b4.z, b4.w};
#pragma unroll
      for (int k = 0; k < 4; ++k) {
        int idx = base + 4 * i + k;
        float xn = (xv[4 * i + k] - mu) * rs * gg[k] + bb[k];
        R[Q0 + (idx >> 5) * LDT + (idx & 31)] = (__bf16)xn;  // wave-local rows
      }
    }
  }
  // No barrier: xn rows are wave-local (written and read by the same wave).

  const int r0 = wid * 32;

  // xn fragments are head-invariant: hoist to regs; xn (Q0 overlay) dies here.
  bf16x8 tA0 = *(const bf16x8*)&R[Q0 + (r0 + l15) * LDT + lh * 8];
  bf16x8 tA1 = *(const bf16x8*)&R[Q0 + (r0 + 16 + l15) * LDT + lh * 8];

  // oacc[mt][nt]: D[q][e'], q = r0+mt*16+lh*4+r, e' = nt*16+l15; seeded with bo.
  f32x4 oacc[2][2];
  {
    float b0 = bo[l15], b1 = bo[16 + l15];
#pragma unroll
    for (int mt = 0; mt < 2; ++mt) {
      oacc[mt][0] = f32x4{b0, b0, b0, b0};
      oacc[mt][1] = f32x4{b1, b1, b1, b1};
    }
  }

  bf16x8 ka0, ka1;

  // Project head hh into q[qo], vT[vo], K (KP); biases folded into MFMA C-in.
  auto do_proj = [&](int hh, int qo, int vo) {
#pragma unroll
    for (int ft = 0; ft < 2; ++ft) {
      int f0 = hh * 32 + ft * 16;
      bf16x8 wqf = *(const bf16x8*)&wqb[(f0 + l15) * 32 + lh * 8];
      bf16x8 wkf = *(const bf16x8*)&wkb[(f0 + l15) * 32 + lh * 8];
      f32x4 bq4 = *(const f32x4*)&bq[f0 + lh * 4];
      f32x4 bk4 = *(const f32x4*)&bk[f0 + lh * 4];
#pragma unroll
      for (int r = 0; r < 4; ++r) bq4[r] *= CQ;
#pragma unroll
      for (int st = 0; st < 2; ++st) {
        bf16x8 tB = (st == 0) ? tA0 : tA1;
        // D[f][s]: f = f0+lh*4+r, s = r0+st*16+l15; C seed = bias(f)
        f32x4 dq = __builtin_amdgcn_mfma_f32_16x16x32_bf16(wqf, tB, bq4, 0, 0, 0);
        f32x4 dk = __builtin_amdgcn_mfma_f32_16x16x32_bf16(wkf, tB, bk4, 0, 0, 0);
        bf16x4 pq, pk;
#pragma unroll
        for (int r = 0; r < 4; ++r) { pq[r] = (__bf16)dq[r]; pk[r] = (__bf16)dk[r]; }
        *(bf16x4*)&R[qo + (r0 + st * 16 + l15) * LDT + ft * 16 + lh * 4] = pq;
        *(bf16x4*)&R[KP + (r0 + st * 16 + l15) * LDT + ft * 16 + lh * 4] = pk;
      }
    }
#pragma unroll
    for (int nt = 0; nt < 2; ++nt) {
      int f0 = hh * 32 + nt * 16;
      bf16x8 wvf = *(const bf16x8*)&wvb[(f0 + l15) * 32 + lh * 8];
      float bvs = bv[f0 + l15];
      f32x4 bv4 = {bvs, bvs, bvs, bvs};
#pragma unroll
      for (int mt = 0; mt < 2; ++mt) {
        bf16x8 tA = (mt == 0) ? tA0 : tA1;
        // D[s][f]: s = r0+mt*16+lh*4+r, f = f0+l15
        f32x4 dv = __builtin_amdgcn_mfma_f32_16x16x32_bf16(tA, wvf, bv4, 0, 0, 0);
        bf16x4 pv;
#pragma unroll
        for (int r = 0; r < 4; ++r) pv[r] = (__bf16)dv[r];
        *(bf16x4*)&R[vo + (nt * 16 + l15) * 128 + ((r0 + mt * 16 + lh * 4) ^ sw)] = pv;
      }
    }
    // K fragments: wave-local rows, consumed straight back into registers.
    ka0 = *(const bf16x8*)&R[KP + (r0 + l15) * LDT + lh * 8];
    ka1 = *(const bf16x8*)&R[KP + (r0 + 16 + l15) * LDT + lh * 8];
  };

  do_proj(0, Q0, V0);

  for (int h = 0; h < NH; ++h) {
    const int p = h & 1;
    const int qo = p ? Q1 : Q0;
    const int vo = p ? V1 : V0;
    __syncthreads();  // A: q[p] + vT[p] ready

    // ---------- scoresT = K·q^T : batch-load all q frags, then 16 MFMAs ----------
    bf16x8 qfr[8];
#pragma unroll
    for (int it = 0; it < 8; ++it)
      qfr[it] = *(const bf16x8*)&R[qo + (it * 16 + l15) * LDT + lh * 8];
    f32x4 st_[2][8];
#pragma unroll
    for (int it = 0; it < 8; ++it) {
      st_[0][it] = __builtin_amdgcn_mfma_f32_16x16x32_bf16(ka0, qfr[it], fz, 0, 0, 0);
      st_[1][it] = __builtin_amdgcn_mfma_f32_16x16x32_bf16(ka1, qfr[it], fz, 0, 0, 0);
    }
    // ---------- project NEXT head into opposite buffers (fills MFMA latency) ----------
    if (h < NH - 1) do_proj(h + 1, p ? Q0 : Q1, p ? V0 : V1);

    // PV's vT fragments depend only on barrier A — batch-issue before softmax.
    bf16x8 va[2][4];
#pragma unroll
    for (int kc = 0; kc < 4; ++kc) {
      va[0][kc] = *(const bf16x8*)&R[vo + (l15) * 128 + ((kc * 32 + lh * 8) ^ sw)];
      va[1][kc] = *(const bf16x8*)&R[vo + (16 + l15) * 128 + ((kc * 32 + lh * 8) ^ sw)];
    }

    // ---------- softmax over query axis (m=0): tree-summed exp2 + DPP ----------
    float inv[2][4];
#pragma unroll
    for (int mt = 0; mt < 2; ++mt)
#pragma unroll
      for (int r = 0; r < 4; ++r) {
        float e0 = __builtin_amdgcn_exp2f(st_[mt][0][r]);
        float e1 = __builtin_amdgcn_exp2f(st_[mt][1][r]);
        float e2 = __builtin_amdgcn_exp2f(st_[mt][2][r]);
        float e3 = __builtin_amdgcn_exp2f(st_[mt][3][r]);
        float e4 = __builtin_amdgcn_exp2f(st_[mt][4][r]);
        float e5 = __builtin_amdgcn_exp2f(st_[mt][5][r]);
        float e6 = __builtin_amdgcn_exp2f(st_[mt][6][r]);
        float e7 = __builtin_amdgcn_exp2f(st_[mt][7][r]);
        st_[mt][0][r] = e0; st_[mt][1][r] = e1; st_[mt][2][r] = e2; st_[mt][3][r] = e3;
        st_[mt][4][r] = e4; st_[mt][5][r] = e5; st_[mt][6][r] = e6; st_[mt][7][r] = e7;
        float ssum = ((e0 + e1) + (e2 + e3)) + ((e4 + e5) + (e6 + e7));
        ssum = row_reduce_add16(ssum);
        inv[mt][r] = __builtin_amdgcn_rcpf(ssum);
      }

    // ---------- P store: normalized, [query][key] swizzled, packed b64 ----------
#pragma unroll
    for (int mt = 0; mt < 2; ++mt)
#pragma unroll
      for (int it = 0; it < 8; ++it) {
        bf16x4 pp;
#pragma unroll
        for (int r = 0; r < 4; ++r) pp[r] = (__bf16)(st_[mt][it][r] * inv[mt][r]);
        *(bf16x4*)&R[PO + (it * 16 + l15) * 128 + ((r0 + mt * 16 + lh * 4) ^ sw)] = pp;
      }
    __syncthreads();  // B: P ready

    // ---------- PV: batch-load all P frags, then 16 MFMAs ----------
    bf16x8 pbr[2][4];
#pragma unroll
    for (int kc = 0; kc < 4; ++kc) {
      pbr[0][kc] = *(const bf16x8*)&R[PO + (r0 + l15) * 128 + ((kc * 32 + lh * 8) ^ sw)];
      pbr[1][kc] = *(const bf16x8*)&R[PO + (r0 + 16 + l15) * 128 + ((kc * 32 + lh * 8) ^ sw)];
    }
    f32x4 p2[2][2];
#pragma unroll
    for (int i = 0; i < 2; ++i)
#pragma unroll
      for (int j = 0; j < 2; ++j) p2[i][j] = fz;
#pragma unroll
    for (int kc = 0; kc < 4; ++kc) {
      p2[0][0] = __builtin_amdgcn_mfma_f32_16x16x32_bf16(va[0][kc], pbr[0][kc], p2[0][0], 0, 0, 0);
      p2[0][1] = __builtin_amdgcn_mfma_f32_16x16x32_bf16(va[0][kc], pbr[1][kc], p2[0][1], 0, 0, 0);
      p2[1][0] = __builtin_amdgcn_mfma_f32_16x16x32_bf16(va[1][kc], pbr[0][kc], p2[1][0], 0, 0, 0);
      p2[1][1] = __builtin_amdgcn_mfma_f32_16x16x32_bf16(va[1][kc], pbr[1][kc], p2[1][1], 0, 0, 0);
    }

    // ---------- outproj from registers (permuted-k, no prod LDS round-trip) ----------
    // virtual k = lh*8+u  <->  e = (u>=4)*16 + lh*4 + (u&3); A and B share it.
    // A(qt): pa[u] = prod[q = r0+qt*16+l15][e(u)] = p2[u>=4][qt][u&3]  (lane-local)
    // B(nt): wof[u] = wo[e' = nt*16+l15][h*32 + e(u)]  (two bf16x4 global loads)
    {
      bf16x8 pa0, pa1;
#pragma unroll
      for (int u = 0; u < 4; ++u) {
        pa0[u] = (__bf16)p2[0][0][u]; pa0[4 + u] = (__bf16)p2[1][0][u];
        pa1[u] = (__bf16)p2[0][1][u]; pa1[4 + u] = (__bf16)p2[1][1][u];
      }
      bf16x4 w0lo = *(const bf16x4*)&wob[(l15) * 256 + h * 32 + lh * 4];
      bf16x4 w0hi = *(const bf16x4*)&wob[(l15) * 256 + h * 32 + 16 + lh * 4];
      bf16x4 w1lo = *(const bf16x4*)&wob[(16 + l15) * 256 + h * 32 + lh * 4];
      bf16x4 w1hi = *(const bf16x4*)&wob[(16 + l15) * 256 + h * 32 + 16 + lh * 4];
      bf16x8 wof0, wof1;
#pragma unroll
      for (int u = 0; u < 4; ++u) {
        wof0[u] = w0lo[u]; wof0[4 + u] = w0hi[u];
        wof1[u] = w1lo[u]; wof1[4 + u] = w1hi[u];
      }
      oacc[0][0] = __builtin_amdgcn_mfma_f32_16x16x32_bf16(pa0, wof0, oacc[0][0], 0, 0, 0);
      oacc[0][1] = __builtin_amdgcn_mfma_f32_16x16x32_bf16(pa0, wof1, oacc[0][1], 0, 0, 0);
      oacc[1][0] = __builtin_amdgcn_mfma_f32_16x16x32_bf16(pa1, wof0, oacc[1][0], 0, 0, 0);
      oacc[1][1] = __builtin_amdgcn_mfma_f32_16x16x32_bf16(pa1, wof1, oacc[1][1], 0, 0, 0);
    }
    // No trailing barrier: next iteration's barrier A orders the cross-wave
    // buffers (opposite-parity q/vT; single P re-store happens after A).
  }

  // ---------------- epilogue: + x (bo already seeded) ----------------
  // oacc[mt][nt][r]: row q = r0+mt*16+lh*4+r, col e' = nt*16+l15
#pragma unroll
  for (int mt = 0; mt < 2; ++mt)
#pragma unroll
    for (int nt = 0; nt < 2; ++nt)
#pragma unroll
      for (int r = 0; r < 4; ++r) {
        int s_ = r0 + mt * 16 + lh * 4 + r;
        int e_ = nt * 16 + l15;
        int idx = s_ * 32 + e_;
        out[b * INSZ + idx] = oacc[mt][nt][r] + xb[idx];
      }
}

extern "C" void kernel_launch(void* const* d_in, const int* in_sizes, int n_in,
                              void* d_out, int out_size, void* d_ws, size_t ws_size,
                              hipStream_t stream) {
  const float* x = (const float*)d_in[0];
  const float* gamma = (const float*)d_in[1];
  const float* beta = (const float*)d_in[2];
  const float* wq = (const float*)d_in[3];
  const float* bq = (const float*)d_in[4];
  const float* wk = (const float*)d_in[5];
  const float* bk = (const float*)d_in[6];
  const float* wv = (const float*)d_in[7];
  const float* bv = (const float*)d_in[8];
  const float* wo = (const float*)d_in[9];
  const float* bo = (const float*)d_in[10];
  float* out = (float*)d_out;
  __bf16* wsb = (__bf16*)d_ws;

  cvt_w<<<128, 256, 0, stream>>>(wq, wk, wv, wo, wsb);
  mha_fused<<<BATCH, TPB, 0, stream>>>(x, gamma, beta, bq, bk, bv, bo, wsb, out);
}